// Round 2
// baseline (6199.816 us; speedup 1.0000x reference)
//
#include <hip/hip_runtime.h>
#include <hip/hip_bf16.h>
#include <math.h>

// Problem constants (fixed by the reference)
constexpr int  Bb   = 16;
constexpr int  Ll   = 4096;
constexpr int  INd  = 192;
constexpr int  Hd   = 512;
constexpr int  Pd   = 128;
constexpr int  Kn   = 6;
constexpr int  OUTd = 192;
constexpr long Mrows = (long)Bb * Ll;   // 65536

// ---------------------------------------------------------------------------
// Prep kernels: weight re-layout + SSM discretization (run every call; cheap)
// ---------------------------------------------------------------------------

__global__ void prep_lam_k(const float* __restrict__ Lre, const float* __restrict__ Lim,
                           const float* __restrict__ lstep,
                           float* lre, float* lim_, float* pre, float* pim,
                           float* cre, float* cim)
{
    int i = blockIdx.x * 256 + threadIdx.x;
    if (i >= Kn * Pd) return;
    float lr = Lre[i], li = Lim[i];
    float st = expf(lstep[i]);
    float ar = lr * st, ai = li * st;          // lam * step
    float er = expf(ar);
    float sn, cs; sincosf(ai, &sn, &cs);
    float br = er * cs, bi = er * sn;          // lam_bar = exp(lam*step)
    lre[i] = br; lim_[i] = bi;
    float e2 = expf(64.f * ar);
    float sn2, cs2; sincosf(64.f * ai, &sn2, &cs2);
    pre[i] = e2 * cs2; pim[i] = e2 * sn2;      // lam_bar^64 (chunk length)
    // coef = (lam_bar - 1) / lam
    float nr = br - 1.f, ni = bi;
    float den = lr * lr + li * li;
    cre[i] = (nr * lr + ni * li) / den;
    cim[i] = (ni * lr - nr * li) / den;
}

// B_bar = coef * (B_re + i B_im); store as (K)(H x 2P): cols 0..127 re, 128..255 im
__global__ void prep_bbar_k(const float* __restrict__ Bre, const float* __restrict__ Bim,
                            const float* __restrict__ cre, const float* __restrict__ cim,
                            float* __restrict__ Wbu)
{
    int i = blockIdx.x * 256 + threadIdx.x;    // 6*512*128
    int p = i & 127;
    int h = (i >> 7) & 511;
    int k = i >> 16;
    float br = Bre[((size_t)(k * 128 + p)) * 512 + h];
    float bi = Bim[((size_t)(k * 128 + p)) * 512 + h];
    float cr = cre[k * 128 + p], ci = cim[k * 128 + p];
    size_t o = (size_t)k * 512 * 256 + (size_t)h * 256;
    Wbu[o + p]        = cr * br - ci * bi;
    Wbu[o + 128 + p]  = cr * bi + ci * br;
}

// Wc: (K)(2P x H): rows 0..127 = 2*C_re^T, rows 128..255 = -2*C_im^T
__global__ void prep_c_k(const float* __restrict__ Cre, const float* __restrict__ Cim,
                         float* __restrict__ Wc)
{
    int i = blockIdx.x * 256 + threadIdx.x;    // 6*512*128
    int p = i & 127;
    int h = (i >> 7) & 511;
    int k = i >> 16;
    float crv = Cre[((size_t)k * 512 + h) * 128 + p];
    float civ = Cim[((size_t)k * 512 + h) * 128 + p];
    size_t o = (size_t)k * 256 * 512;
    Wc[o + (size_t)p * 512 + h]         =  2.f * crv;
    Wc[o + (size_t)(128 + p) * 512 + h] = -2.f * civ;
}

__global__ void prep_glu_k(const float* __restrict__ Wg, float* __restrict__ Wt)
{
    int i = blockIdx.x * 256 + threadIdx.x;    // 6*512*512
    int in_ = i & 511;
    int ot  = (i >> 9) & 511;
    int k   = i >> 18;
    Wt[(size_t)k * 262144 + (size_t)in_ * 512 + ot] =
        Wg[(size_t)k * 262144 + (size_t)ot * 512 + in_];
}

__global__ void prep_enc_k(const float* __restrict__ We, float* __restrict__ Wt)
{
    int i = blockIdx.x * 256 + threadIdx.x;    // 192*512
    if (i >= INd * Hd) return;
    int h   = i & 511;
    int in_ = i >> 9;
    Wt[(size_t)in_ * 512 + h] = We[(size_t)h * 192 + in_];
}

__global__ void prep_dec_k(const float* __restrict__ Wd, float* __restrict__ Wt)
{
    int i = blockIdx.x * 256 + threadIdx.x;    // 512*192
    if (i >= Hd * OUTd) return;
    int o = i % 192;
    int h = i / 192;
    Wt[(size_t)h * 192 + o] = Wd[(size_t)o * 512 + h];
}

// ---------------------------------------------------------------------------
// LayerNorm: one wave per row of 512
// ---------------------------------------------------------------------------
__global__ __launch_bounds__(256)
void ln_k(const float* __restrict__ x, float* __restrict__ o,
          const float* __restrict__ sc, const float* __restrict__ bi)
{
    const int  lane = threadIdx.x & 63;
    const long row  = (long)blockIdx.x * 4 + (threadIdx.x >> 6);
    const float* p = x + row * 512 + lane * 8;
    float v[8];
    *(float4*)&v[0] = *(const float4*)p;
    *(float4*)&v[4] = *(const float4*)(p + 4);
    float s = 0.f;
#pragma unroll
    for (int j = 0; j < 8; ++j) s += v[j];
#pragma unroll
    for (int m = 1; m < 64; m <<= 1) s += __shfl_xor(s, m, 64);
    const float mu = s * (1.f / 512.f);
    float q = 0.f;
#pragma unroll
    for (int j = 0; j < 8; ++j) { float d = v[j] - mu; q += d * d; }
#pragma unroll
    for (int m = 1; m < 64; m <<= 1) q += __shfl_xor(q, m, 64);
    const float rs = rsqrtf(q * (1.f / 512.f) + 1e-5f);
    float sv[8], bv[8], r[8];
    *(float4*)&sv[0] = *(const float4*)(sc + lane * 8);
    *(float4*)&sv[4] = *(const float4*)(sc + lane * 8 + 4);
    *(float4*)&bv[0] = *(const float4*)(bi + lane * 8);
    *(float4*)&bv[4] = *(const float4*)(bi + lane * 8 + 4);
#pragma unroll
    for (int j = 0; j < 8; ++j) r[j] = (v[j] - mu) * rs * sv[j] + bv[j];
    float* op = o + row * 512 + lane * 8;
    *(float4*)op       = *(float4*)&r[0];
    *(float4*)(op + 4) = *(float4*)&r[4];
}

// ---------------------------------------------------------------------------
// Chunked linear recurrence x_t = lam_bar * x_{t-1} + Bu_t  (complex, LTI)
// Bu layout: (Mg) x 256, cols 0..127 = re, 128..255 = im.  nB sequences.
// ---------------------------------------------------------------------------
__global__ __launch_bounds__(256)
void scan_local_k(const float* __restrict__ Bu, float* __restrict__ fin,
                  const float* __restrict__ lre, const float* __restrict__ lim, int nB)
{
    const int g = blockIdx.x * 256 + threadIdx.x;   // nB*64*128
    const int p = g & 127;
    const int c = (g >> 7) & 63;
    const int b = g >> 13;
    if (b >= nB) return;
    const float ar = lre[p], ai = lim[p];
    const float* base = Bu + ((long)(b * Ll + c * 64)) * 256 + p;
    float xr = 0.f, xi = 0.f;
#pragma unroll 4
    for (int j = 0; j < 64; ++j) {
        float br  = base[j * 256];
        float bi2 = base[j * 256 + 128];
        float nr = fmaf(ar, xr, fmaf(-ai, xi, br));
        float ni = fmaf(ar, xi, fmaf( ai, xr, bi2));
        xr = nr; xi = ni;
    }
    long o = ((long)(b * 64 + c)) * 256 + p;
    fin[o] = xr; fin[o + 128] = xi;
}

__global__ void scan_carry_k(const float* __restrict__ fin, float* __restrict__ carry,
                             const float* __restrict__ pre, const float* __restrict__ pim,
                             int nB)
{
    const int g = blockIdx.x * 256 + threadIdx.x;   // nB*128
    if (g >= nB * 128) return;
    const int p = g & 127;
    const int b = g >> 7;
    const float pr = pre[p], pi = pim[p];
    float cr = 0.f, ci = 0.f;
    for (int c = 0; c < 64; ++c) {
        long o = ((long)(b * 64 + c)) * 256 + p;
        float fr = fin[o], fi = fin[o + 128];
        carry[o] = cr; carry[o + 128] = ci;     // prefix BEFORE this chunk
        float nr = fmaf(pr, cr, fmaf(-pi, ci, fr));
        float ni = fmaf(pr, ci, fmaf( pi, cr, fi));
        cr = nr; ci = ni;
    }
}

// replay with carry; writes xs in place over Bu (element read happens before write)
__global__ __launch_bounds__(256)
void scan_final_k(float* __restrict__ Bu, const float* __restrict__ carry,
                  const float* __restrict__ lre, const float* __restrict__ lim, int nB)
{
    const int g = blockIdx.x * 256 + threadIdx.x;
    const int p = g & 127;
    const int c = (g >> 7) & 63;
    const int b = g >> 13;
    if (b >= nB) return;
    const float ar = lre[p], ai = lim[p];
    long co = ((long)(b * 64 + c)) * 256 + p;
    float xr = carry[co], xi = carry[co + 128];
    float* base = Bu + ((long)(b * Ll + c * 64)) * 256 + p;
#pragma unroll 4
    for (int j = 0; j < 64; ++j) {
        float br  = base[j * 256];
        float bi2 = base[j * 256 + 128];
        float nr = fmaf(ar, xr, fmaf(-ai, xi, br));
        float ni = fmaf(ar, xi, fmaf( ai, xr, bi2));
        xr = nr; xi = ni;
        base[j * 256]       = xr;
        base[j * 256 + 128] = xi;
    }
}

// ---------------------------------------------------------------------------
// fp32 tiled GEMM: C(MxN) = A(MxK) @ Bw(KxN), tile 128 x BN_T, BK=16,
// 256 threads, thread-tile 8 x (BN_T/16). Epilogues:
//   0: store    1: +bias    2: gelu(acc + aux1*bias)  [y-GEMM; C may alias aux1]
//   3: C += aux1 * sigmoid(acc + bias)                [GLU; C read+write, skip]
// ---------------------------------------------------------------------------
template<int BN_T, int EPI>
__global__ __launch_bounds__(256)
void gemm_k(const float* __restrict__ A, const float* __restrict__ Bw,
            float* C, int N, int Kd,
            const float* __restrict__ bias, const float* aux1)
{
    constexpr int BM = 128, BK = 16;
    constexpr int TN = BN_T / 16;          // 8 or 4
    constexpr int AP = BM + 4;             // LDS pad (keeps 16B alignment)
    constexpr int BP = BN_T + 4;
    __shared__ float As[BK][AP];
    __shared__ float Bs[BK][BP];

    const int  tid = threadIdx.x;
    const long bm  = (long)blockIdx.x * BM;
    const int  bn  = blockIdx.y * BN_T;
    const int  tm  = (tid >> 4) * 8;
    const int  tn  = (tid & 15) * TN;

    float acc[8][TN];
#pragma unroll
    for (int i = 0; i < 8; ++i)
#pragma unroll
        for (int j = 0; j < TN; ++j) acc[i][j] = 0.f;

    const int ar = tid >> 1;               // A-stage row 0..127
    const int ak = (tid & 1) * 8;          // A-stage k offset

    for (int k0 = 0; k0 < Kd; k0 += BK) {
        const float4 a0 = *(const float4*)(A + (bm + ar) * (long)Kd + k0 + ak);
        const float4 a1 = *(const float4*)(A + (bm + ar) * (long)Kd + k0 + ak + 4);
        float4 b0, b1;
        if constexpr (BN_T == 128) {
            const int bk0 = tid >> 5;              // rows bk0 and bk0+8
            const int bq  = (tid & 31) * 4;
            b0 = *(const float4*)(Bw + (long)(k0 + bk0) * N + bn + bq);
            b1 = *(const float4*)(Bw + (long)(k0 + bk0 + 8) * N + bn + bq);
        } else {
            const int bk0 = tid >> 4;
            const int bq  = (tid & 15) * 4;
            b0 = *(const float4*)(Bw + (long)(k0 + bk0) * N + bn + bq);
        }
        __syncthreads();
        As[ak + 0][ar] = a0.x; As[ak + 1][ar] = a0.y;
        As[ak + 2][ar] = a0.z; As[ak + 3][ar] = a0.w;
        As[ak + 4][ar] = a1.x; As[ak + 5][ar] = a1.y;
        As[ak + 6][ar] = a1.z; As[ak + 7][ar] = a1.w;
        if constexpr (BN_T == 128) {
            *(float4*)&Bs[(tid >> 5)][(tid & 31) * 4]     = b0;
            *(float4*)&Bs[(tid >> 5) + 8][(tid & 31) * 4] = b1;
        } else {
            *(float4*)&Bs[(tid >> 4)][(tid & 15) * 4] = b0;
        }
        __syncthreads();
#pragma unroll
        for (int kk = 0; kk < BK; ++kk) {
            float av[8], bv[TN];
            *(float4*)&av[0] = *(const float4*)&As[kk][tm];
            *(float4*)&av[4] = *(const float4*)&As[kk][tm + 4];
            *(float4*)&bv[0] = *(const float4*)&Bs[kk][tn];
            if constexpr (TN == 8)
                *(float4*)&bv[4] = *(const float4*)&Bs[kk][tn + 4];
#pragma unroll
            for (int i = 0; i < 8; ++i)
#pragma unroll
                for (int j = 0; j < TN; ++j)
                    acc[i][j] = fmaf(av[i], bv[j], acc[i][j]);
        }
    }

#pragma unroll
    for (int i = 0; i < 8; ++i) {
        const long off = (bm + tm + i) * (long)N + bn + tn;
#pragma unroll
        for (int g = 0; g < TN / 4; ++g) {
            float vv[4];
#pragma unroll
            for (int j = 0; j < 4; ++j) vv[j] = acc[i][g * 4 + j];
            if constexpr (EPI == 1) {
                const float4 bb = *(const float4*)(bias + bn + tn + g * 4);
                vv[0] += bb.x; vv[1] += bb.y; vv[2] += bb.z; vv[3] += bb.w;
            } else if constexpr (EPI == 2) {
                const float4 bb = *(const float4*)(bias + bn + tn + g * 4);
                const float4 uu = *(const float4*)(aux1 + off + g * 4);
                vv[0] += uu.x * bb.x; vv[1] += uu.y * bb.y;
                vv[2] += uu.z * bb.z; vv[3] += uu.w * bb.w;
#pragma unroll
                for (int j = 0; j < 4; ++j) {
                    float xg = vv[j];
                    float t  = tanhf(0.7978845608028654f * (xg + 0.044715f * xg * xg * xg));
                    vv[j] = 0.5f * xg * (1.f + t);
                }
            } else if constexpr (EPI == 3) {
                const float4 bb = *(const float4*)(bias + bn + tn + g * 4);
                const float4 gg = *(const float4*)(aux1 + off + g * 4);
                const float4 hh = *(const float4*)(C + off + g * 4);
                float z0 = vv[0] + bb.x, z1 = vv[1] + bb.y;
                float z2 = vv[2] + bb.z, z3 = vv[3] + bb.w;
                vv[0] = hh.x + gg.x / (1.f + expf(-z0));
                vv[1] = hh.y + gg.y / (1.f + expf(-z1));
                vv[2] = hh.z + gg.z / (1.f + expf(-z2));
                vv[3] = hh.w + gg.w / (1.f + expf(-z3));
            }
            *(float4*)(C + off + g * 4) = make_float4(vv[0], vv[1], vv[2], vv[3]);
        }
    }
}

// ---------------------------------------------------------------------------
// Launch.  Workspace-adaptive: process the 16 independent sequences in G
// groups so the per-group activations (h, u, Bu) fit in ws_size.
// ---------------------------------------------------------------------------
extern "C" void kernel_launch(void* const* d_in, const int* in_sizes, int n_in,
                              void* d_out, int out_size, void* d_ws, size_t ws_size,
                              hipStream_t stream)
{
    const float* x        = (const float*)d_in[0];
    const float* W_enc    = (const float*)d_in[1];
    const float* b_enc    = (const float*)d_in[2];
    const float* ln_scale = (const float*)d_in[3];
    const float* ln_bias  = (const float*)d_in[4];
    const float* Lre      = (const float*)d_in[5];
    const float* Lim      = (const float*)d_in[6];
    const float* B_re     = (const float*)d_in[7];
    const float* B_im     = (const float*)d_in[8];
    const float* C_re     = (const float*)d_in[9];
    const float* C_im     = (const float*)d_in[10];
    const float* Dv       = (const float*)d_in[11];
    const float* log_step = (const float*)d_in[12];
    const float* W_glu    = (const float*)d_in[13];
    const float* b_glu    = (const float*)d_in[14];
    const float* W_dec    = (const float*)d_in[15];
    const float* b_dec    = (const float*)d_in[16];
    float* out = (float*)d_out;

    // ---- fixed-footprint allocations (weights, lambda tables, scan scratch)
    char* w = (char*)d_ws;
    auto alloc = [&](size_t nfloats) { float* p = (float*)w; w += nfloats * 4; return p; };
    float* lam_re = alloc(768);
    float* lam_im = alloc(768);
    float* pow_re = alloc(768);
    float* pow_im = alloc(768);
    float* coef_re= alloc(768);
    float* coef_im= alloc(768);
    float* Wenc_t = alloc((size_t)INd * Hd);
    float* Wbu    = alloc((size_t)Kn * Hd * 256);
    float* Wc     = alloc((size_t)Kn * 256 * Hd);
    float* Wglu_t = alloc((size_t)Kn * Hd * Hd);
    float* Wdec_t = alloc((size_t)Hd * OUTd);
    float* fin    = alloc((size_t)Bb * 64 * 256);
    float* carry  = alloc((size_t)Bb * 64 * 256);
    const size_t fixed_bytes = (size_t)(w - (char*)d_ws);

    // ---- choose group count G (power of 2) so activations fit
    int G = 1;
    for (; G < 16; G *= 2) {
        size_t Mg = Mrows / G;
        size_t need = fixed_bytes + Mg * (size_t)(Hd + Hd + 256) * 4;
        if (need <= ws_size) break;
    }
    const long Bg = Bb / G;            // sequences per group
    const long Mg = Bg * Ll;           // rows per group

    float* h  = alloc((size_t)Mg * Hd);
    float* u  = alloc((size_t)Mg * Hd);   // LN-out; later aliased as g (in-place gelu)
    float* Bu = alloc((size_t)Mg * 256);  // Bu, then xs in place

    // ---- prep (once per call; cheap)
    prep_lam_k <<<3,    256, 0, stream>>>(Lre, Lim, log_step, lam_re, lam_im,
                                          pow_re, pow_im, coef_re, coef_im);
    prep_bbar_k<<<1536, 256, 0, stream>>>(B_re, B_im, coef_re, coef_im, Wbu);
    prep_c_k   <<<1536, 256, 0, stream>>>(C_re, C_im, Wc);
    prep_glu_k <<<6144, 256, 0, stream>>>(W_glu, Wglu_t);
    prep_enc_k <<<384,  256, 0, stream>>>(W_enc, Wenc_t);
    prep_dec_k <<<384,  256, 0, stream>>>(W_dec, Wdec_t);

    const dim3 blk(256);
    const int gx = (int)(Mg / 128);        // GEMM grid.x
    for (int g0 = 0; g0 < G; ++g0) {
        const float* xg   = x   + (size_t)g0 * Mg * INd;
        float*       outg = out + (size_t)g0 * Mg * OUTd;

        // encoder: h = x @ Wenc_t + b_enc   (Mg x 512, K=192)
        gemm_k<128, 1><<<dim3(gx, 4), blk, 0, stream>>>(xg, Wenc_t, h, 512, 192, b_enc, nullptr);

        for (int k = 0; k < Kn; ++k) {
            ln_k<<<(int)(Mg / 4), 256, 0, stream>>>(h, u, ln_scale + k * 512, ln_bias + k * 512);
            // Bu = u @ Wbu[k]   (Mg x 256, K=512)
            gemm_k<128, 0><<<dim3(gx, 2), blk, 0, stream>>>(
                u, Wbu + (size_t)k * Hd * 256, Bu, 256, 512, nullptr, nullptr);
            scan_local_k<<<(int)(Bg * 32), 256, 0, stream>>>(
                Bu, fin, lam_re + k * 128, lam_im + k * 128, (int)Bg);
            scan_carry_k<<<(int)((Bg * 128 + 255) / 256), 256, 0, stream>>>(
                fin, carry, pow_re + k * 128, pow_im + k * 128, (int)Bg);
            scan_final_k<<<(int)(Bg * 32), 256, 0, stream>>>(
                Bu, carry, lam_re + k * 128, lam_im + k * 128, (int)Bg);
            // g = gelu(xs @ Wc[k] + u*D[k])  → written in place over u
            gemm_k<128, 2><<<dim3(gx, 4), blk, 0, stream>>>(
                Bu, Wc + (size_t)k * 256 * Hd, u, 512, 256, Dv + k * 512, u);
            // h = h + g * sigmoid(g @ Wglu_t[k] + b_glu[k])
            gemm_k<128, 3><<<dim3(gx, 4), blk, 0, stream>>>(
                u, Wglu_t + (size_t)k * Hd * Hd, h, 512, 512, b_glu + k * 512, u);
        }
        // decoder: out = h @ Wdec_t + b_dec  (Mg x 192, K=512)
        gemm_k<64, 1><<<dim3(gx, 3), blk, 0, stream>>>(h, Wdec_t, outg, 192, 512, b_dec, nullptr);
    }
}

// Round 3
// 3457.632 us; speedup vs baseline: 1.7931x; 1.7931x over previous
//
#include <hip/hip_runtime.h>
#include <hip/hip_bf16.h>
#include <math.h>

// Problem constants
constexpr int  Bb   = 16;
constexpr int  Ll   = 4096;
constexpr int  INd  = 192;
constexpr int  Hd   = 512;
constexpr int  Kn   = 6;
constexpr int  OUTd = 192;
constexpr long Mrows = (long)Bb * Ll;   // 65536

typedef _Float16 f16;
typedef _Float16 f16x8 __attribute__((ext_vector_type(8)));
typedef float    f32x4 __attribute__((ext_vector_type(4)));

__device__ inline void split16(float v, f16& hi, f16& lo) {
    f16 h = (f16)v; hi = h; lo = (f16)(v - (float)h);
}

// ---------------------------------------------------------------------------
// Prep: SSM discretization + weight split-convert (all weights kept N x K)
// ---------------------------------------------------------------------------
__global__ void prep_lam_k(const float* __restrict__ Lre, const float* __restrict__ Lim,
                           const float* __restrict__ lstep,
                           float* lre, float* lim_, float* pre, float* pim,
                           float* cre, float* cim)
{
    int i = blockIdx.x * 256 + threadIdx.x;
    if (i >= Kn * 128) return;
    float lr = Lre[i], li = Lim[i];
    float st = expf(lstep[i]);
    float ar = lr * st, ai = li * st;
    float er = expf(ar);
    float sn, cs; sincosf(ai, &sn, &cs);
    float br = er * cs, bi = er * sn;          // lam_bar
    lre[i] = br; lim_[i] = bi;
    float e2 = expf(64.f * ar);
    float sn2, cs2; sincosf(64.f * ai, &sn2, &cs2);
    pre[i] = e2 * cs2; pim[i] = e2 * sn2;      // lam_bar^64
    float nr = br - 1.f, ni = bi;
    float den = lr * lr + li * li;
    cre[i] = (nr * lr + ni * li) / den;        // (lam_bar-1)/lam
    cim[i] = (ni * lr - nr * li) / den;
}

// Wbu[k]: (256 x 512) rows n<128: Re(B_bar[p=n]), n>=128: Im. split f16.
__global__ void prep_bbar_k(const float* __restrict__ Bre, const float* __restrict__ Bim,
                            const float* __restrict__ cre, const float* __restrict__ cim,
                            f16* __restrict__ Wh, f16* __restrict__ Wl)
{
    int i = blockIdx.x * 256 + threadIdx.x;    // 6*128*512
    int h = i & 511;
    int p = (i >> 9) & 127;
    int k = i >> 16;
    float br = Bre[((size_t)(k * 128 + p)) * 512 + h];
    float bi = Bim[((size_t)(k * 128 + p)) * 512 + h];
    float cr = cre[k * 128 + p], ci = cim[k * 128 + p];
    size_t oR = (size_t)(k * 256 + p) * 512 + h;
    size_t oI = (size_t)(k * 256 + 128 + p) * 512 + h;
    split16(cr * br - ci * bi, Wh[oR], Wl[oR]);
    split16(cr * bi + ci * br, Wh[oI], Wl[oI]);
}

// Wc[k]: (512 x 256): row h, col p<128: 2*C_re[h][p]; col 128+p: -2*C_im[h][p]
__global__ void prep_c_k(const float* __restrict__ Cre, const float* __restrict__ Cim,
                         f16* __restrict__ Wh, f16* __restrict__ Wl)
{
    int i = blockIdx.x * 256 + threadIdx.x;    // 6*512*128
    int p = i & 127;
    int h = (i >> 7) & 511;
    int k = i >> 16;
    float crv = Cre[((size_t)k * 512 + h) * 128 + p];
    float civ = Cim[((size_t)k * 512 + h) * 128 + p];
    size_t o = ((size_t)k * 512 + h) * 256;
    split16( 2.f * crv, Wh[o + p],       Wl[o + p]);
    split16(-2.f * civ, Wh[o + 128 + p], Wl[o + 128 + p]);
}

__global__ void split_w_k(const float* __restrict__ W, f16* __restrict__ Wh,
                          f16* __restrict__ Wl, long n)
{
    long i = (long)blockIdx.x * 256 + threadIdx.x;
    if (i >= n) return;
    split16(W[i], Wh[i], Wl[i]);
}

// activation split: 8 elems/thread, vectorized
__global__ __launch_bounds__(256)
void split_a_k(const float* __restrict__ in, f16* __restrict__ oh,
               f16* __restrict__ ol, long n8)
{
    long i = (long)blockIdx.x * 256 + threadIdx.x;
    if (i >= n8) return;
    const float* p = in + i * 8;
    float v[8];
    *(float4*)&v[0] = *(const float4*)p;
    *(float4*)&v[4] = *(const float4*)(p + 4);
    f16x8 vh, vl;
#pragma unroll
    for (int j = 0; j < 8; ++j) { f16 a, b; split16(v[j], a, b); vh[j] = a; vl[j] = b; }
    *(f16x8*)(oh + i * 8) = vh;
    *(f16x8*)(ol + i * 8) = vl;
}

// ---------------------------------------------------------------------------
// LayerNorm: one wave per row of 512; writes split f16
// ---------------------------------------------------------------------------
__global__ __launch_bounds__(256)
void ln_k(const float* __restrict__ x, f16* __restrict__ oh, f16* __restrict__ ol,
          const float* __restrict__ sc, const float* __restrict__ bi)
{
    const int  lane = threadIdx.x & 63;
    const long row  = (long)blockIdx.x * 4 + (threadIdx.x >> 6);
    const float* p = x + row * 512 + lane * 8;
    float v[8];
    *(float4*)&v[0] = *(const float4*)p;
    *(float4*)&v[4] = *(const float4*)(p + 4);
    float s = 0.f;
#pragma unroll
    for (int j = 0; j < 8; ++j) s += v[j];
#pragma unroll
    for (int m = 1; m < 64; m <<= 1) s += __shfl_xor(s, m, 64);
    const float mu = s * (1.f / 512.f);
    float q = 0.f;
#pragma unroll
    for (int j = 0; j < 8; ++j) { float d = v[j] - mu; q += d * d; }
#pragma unroll
    for (int m = 1; m < 64; m <<= 1) q += __shfl_xor(q, m, 64);
    const float rs = rsqrtf(q * (1.f / 512.f) + 1e-5f);
    float sv[8], bv[8];
    *(float4*)&sv[0] = *(const float4*)(sc + lane * 8);
    *(float4*)&sv[4] = *(const float4*)(sc + lane * 8 + 4);
    *(float4*)&bv[0] = *(const float4*)(bi + lane * 8);
    *(float4*)&bv[4] = *(const float4*)(bi + lane * 8 + 4);
    f16x8 vh, vl;
#pragma unroll
    for (int j = 0; j < 8; ++j) {
        float r = (v[j] - mu) * rs * sv[j] + bv[j];
        f16 a, b; split16(r, a, b); vh[j] = a; vl[j] = b;
    }
    *(f16x8*)(oh + row * 512 + lane * 8) = vh;
    *(f16x8*)(ol + row * 512 + lane * 8) = vl;
}

// ---------------------------------------------------------------------------
// Chunked linear recurrence (complex, fp32 state). Bu: (Mg x 256) fp32.
// ---------------------------------------------------------------------------
__global__ __launch_bounds__(256)
void scan_local_k(const float* __restrict__ Bu, float* __restrict__ fin,
                  const float* __restrict__ lre, const float* __restrict__ lim, int nB)
{
    const int g = blockIdx.x * 256 + threadIdx.x;
    const int p = g & 127;
    const int c = (g >> 7) & 63;
    const int b = g >> 13;
    if (b >= nB) return;
    const float ar = lre[p], ai = lim[p];
    const float* base = Bu + ((long)(b * Ll + c * 64)) * 256 + p;
    float xr = 0.f, xi = 0.f;
#pragma unroll 4
    for (int j = 0; j < 64; ++j) {
        float br  = base[j * 256];
        float bi2 = base[j * 256 + 128];
        float nr = fmaf(ar, xr, fmaf(-ai, xi, br));
        float ni = fmaf(ar, xi, fmaf( ai, xr, bi2));
        xr = nr; xi = ni;
    }
    long o = ((long)(b * 64 + c)) * 256 + p;
    fin[o] = xr; fin[o + 128] = xi;
}

__global__ void scan_carry_k(const float* __restrict__ fin, float* __restrict__ carry,
                             const float* __restrict__ pre, const float* __restrict__ pim,
                             int nB)
{
    const int g = blockIdx.x * 256 + threadIdx.x;
    if (g >= nB * 128) return;
    const int p = g & 127;
    const int b = g >> 7;
    const float pr = pre[p], pi = pim[p];
    float cr = 0.f, ci = 0.f;
    for (int c = 0; c < 64; ++c) {
        long o = ((long)(b * 64 + c)) * 256 + p;
        float fr = fin[o], fi = fin[o + 128];
        carry[o] = cr; carry[o + 128] = ci;
        float nr = fmaf(pr, cr, fmaf(-pi, ci, fr));
        float ni = fmaf(pr, ci, fmaf( pi, cr, fi));
        cr = nr; ci = ni;
    }
}

// replay with carry; writes xs as split f16 (GEMM A operand)
__global__ __launch_bounds__(256)
void scan_final_k(const float* __restrict__ Bu, const float* __restrict__ carry,
                  f16* __restrict__ xh, f16* __restrict__ xl,
                  const float* __restrict__ lre, const float* __restrict__ lim, int nB)
{
    const int g = blockIdx.x * 256 + threadIdx.x;
    const int p = g & 127;
    const int c = (g >> 7) & 63;
    const int b = g >> 13;
    if (b >= nB) return;
    const float ar = lre[p], ai = lim[p];
    long co = ((long)(b * 64 + c)) * 256 + p;
    float xr = carry[co], xi = carry[co + 128];
    const float* base = Bu + ((long)(b * Ll + c * 64)) * 256 + p;
    f16* bh = xh + ((long)(b * Ll + c * 64)) * 256 + p;
    f16* bl = xl + ((long)(b * Ll + c * 64)) * 256 + p;
#pragma unroll 4
    for (int j = 0; j < 64; ++j) {
        float br  = base[j * 256];
        float bi2 = base[j * 256 + 128];
        float nr = fmaf(ar, xr, fmaf(-ai, xi, br));
        float ni = fmaf(ar, xi, fmaf( ai, xr, bi2));
        xr = nr; xi = ni;
        split16(xr, bh[j * 256],       bl[j * 256]);
        split16(xi, bh[j * 256 + 128], bl[j * 256 + 128]);
    }
}

// ---------------------------------------------------------------------------
// Split-fp16 MFMA GEMM: C(MxN) = (Ah+Al)(Bh+Bl)^T-ish, A: MxK, B: NxK (!),
// 3-term Markidis. Tile BM=128 x BN(128|64), BK=32, 256 thr = 4 waves.
// Grid: (N/BN, M/128)  — N fastest so same-A blocks are L2-adjacent.
// EPI: 0 store fp32 | 1 +bias store fp32 | 2 gelu(acc+(auxh+auxl)*bias)->split
//    | 3 C += (auxh+auxl)*sigmoid(acc+bias)
// ---------------------------------------------------------------------------
template<int BN, int EPI>
__global__ __launch_bounds__(256)
void mgemm_k(const f16* __restrict__ Ah, const f16* __restrict__ Al,
             const f16* __restrict__ Bh, const f16* __restrict__ Bl,
             float* __restrict__ C, int N, int Kd,
             const float* __restrict__ bias,
             const f16* __restrict__ auxh, const f16* __restrict__ auxl,
             f16* __restrict__ outh, f16* __restrict__ outl)
{
    constexpr int BM = 128, BK = 32, LDA = 40;
    constexpr int WM = (BN == 128) ? 64 : 32;
    constexpr int FM = WM / 16;            // 4 or 2
    constexpr int FN = 4;                  // WN = 64
    __shared__ __align__(16) f16 AsH[BM][LDA], AsL[BM][LDA];
    __shared__ __align__(16) f16 BsH[BN][LDA], BsL[BN][LDA];

    const int tid  = threadIdx.x;
    const int wid  = tid >> 6;
    const int lane = tid & 63;
    const int l15  = lane & 15;
    const int l4   = lane >> 4;
    const int wm   = (BN == 128) ? (wid >> 1) : wid;
    const int wn   = (BN == 128) ? (wid & 1) : 0;

    const long bm = (long)blockIdx.y * BM;
    const int  bn = blockIdx.x * BN;

    f32x4 acc[FM][FN];
#pragma unroll
    for (int i = 0; i < FM; ++i)
#pragma unroll
        for (int j = 0; j < FN; ++j) acc[i][j] = (f32x4){0.f, 0.f, 0.f, 0.f};

    const int arow = tid >> 1;             // 0..127
    const int akc  = (tid & 1) * 16;       // 0|16
    const int brow = (BN == 128) ? (tid >> 1) : (tid >> 2);
    const int bkc  = (BN == 128) ? ((tid & 1) * 16) : ((tid & 3) * 8);

    for (int k0 = 0; k0 < Kd; k0 += BK) {
        const long aoff = (bm + arow) * (long)Kd + k0 + akc;
        f16x8 a0h = *(const f16x8*)(Ah + aoff);
        f16x8 a1h = *(const f16x8*)(Ah + aoff + 8);
        f16x8 a0l = *(const f16x8*)(Al + aoff);
        f16x8 a1l = *(const f16x8*)(Al + aoff + 8);
        const long boff = (long)(bn + brow) * Kd + k0 + bkc;
        f16x8 b0h, b1h, b0l, b1l;
        b0h = *(const f16x8*)(Bh + boff);
        b0l = *(const f16x8*)(Bl + boff);
        if constexpr (BN == 128) {
            b1h = *(const f16x8*)(Bh + boff + 8);
            b1l = *(const f16x8*)(Bl + boff + 8);
        }
        __syncthreads();
        *(f16x8*)&AsH[arow][akc]     = a0h;
        *(f16x8*)&AsH[arow][akc + 8] = a1h;
        *(f16x8*)&AsL[arow][akc]     = a0l;
        *(f16x8*)&AsL[arow][akc + 8] = a1l;
        *(f16x8*)&BsH[brow][bkc] = b0h;
        *(f16x8*)&BsL[brow][bkc] = b0l;
        if constexpr (BN == 128) {
            *(f16x8*)&BsH[brow][bkc + 8] = b1h;
            *(f16x8*)&BsL[brow][bkc + 8] = b1l;
        }
        __syncthreads();

        f16x8 afh[FM], afl[FM], bfh[FN], bfl[FN];
#pragma unroll
        for (int i = 0; i < FM; ++i) {
            afh[i] = *(const f16x8*)&AsH[wm * WM + i * 16 + l15][l4 * 8];
            afl[i] = *(const f16x8*)&AsL[wm * WM + i * 16 + l15][l4 * 8];
        }
#pragma unroll
        for (int j = 0; j < FN; ++j) {
            bfh[j] = *(const f16x8*)&BsH[wn * 64 + j * 16 + l15][l4 * 8];
            bfl[j] = *(const f16x8*)&BsL[wn * 64 + j * 16 + l15][l4 * 8];
        }
#pragma unroll
        for (int i = 0; i < FM; ++i)
#pragma unroll
            for (int j = 0; j < FN; ++j) {
                acc[i][j] = __builtin_amdgcn_mfma_f32_16x16x32_f16(afh[i], bfh[j], acc[i][j], 0, 0, 0);
                acc[i][j] = __builtin_amdgcn_mfma_f32_16x16x32_f16(afh[i], bfl[j], acc[i][j], 0, 0, 0);
                acc[i][j] = __builtin_amdgcn_mfma_f32_16x16x32_f16(afl[i], bfh[j], acc[i][j], 0, 0, 0);
            }
    }

#pragma unroll
    for (int i = 0; i < FM; ++i)
#pragma unroll
        for (int j = 0; j < FN; ++j) {
            const int n = bn + wn * 64 + j * 16 + l15;
            float bv = 0.f;
            if constexpr (EPI != 0) bv = bias[n];
#pragma unroll
            for (int r = 0; r < 4; ++r) {
                const long m = bm + wm * WM + i * 16 + l4 * 4 + r;
                const long off = m * N + n;
                float v = acc[i][j][r];
                if constexpr (EPI == 0) {
                    C[off] = v;
                } else if constexpr (EPI == 1) {
                    C[off] = v + bv;
                } else if constexpr (EPI == 2) {
                    float u = (float)auxh[off] + (float)auxl[off];
                    float y = v + u * bv;
                    float t = tanhf(0.7978845608028654f * (y + 0.044715f * y * y * y));
                    float g = 0.5f * y * (1.f + t);
                    split16(g, outh[off], outl[off]);
                } else {  // EPI == 3
                    float gfull = (float)auxh[off] + (float)auxl[off];
                    float z = v + bv;
                    C[off] += gfull / (1.f + expf(-z));
                }
            }
        }
}

// ---------------------------------------------------------------------------
// Launch (workspace-adaptive grouping over the 16 independent sequences)
// ---------------------------------------------------------------------------
extern "C" void kernel_launch(void* const* d_in, const int* in_sizes, int n_in,
                              void* d_out, int out_size, void* d_ws, size_t ws_size,
                              hipStream_t stream)
{
    const float* x        = (const float*)d_in[0];
    const float* W_enc    = (const float*)d_in[1];
    const float* b_enc    = (const float*)d_in[2];
    const float* ln_scale = (const float*)d_in[3];
    const float* ln_bias  = (const float*)d_in[4];
    const float* Lre      = (const float*)d_in[5];
    const float* Lim      = (const float*)d_in[6];
    const float* B_re     = (const float*)d_in[7];
    const float* B_im     = (const float*)d_in[8];
    const float* C_re     = (const float*)d_in[9];
    const float* C_im     = (const float*)d_in[10];
    const float* Dv       = (const float*)d_in[11];
    const float* log_step = (const float*)d_in[12];
    const float* W_glu    = (const float*)d_in[13];
    const float* b_glu    = (const float*)d_in[14];
    const float* W_dec    = (const float*)d_in[15];
    const float* b_dec    = (const float*)d_in[16];
    float* out = (float*)d_out;

    char* w = (char*)d_ws;
    auto alloc = [&](size_t nbytes) { char* p = w; w += (nbytes + 255) & ~255ull; return p; };

    float* lam_re = (float*)alloc(768 * 4);
    float* lam_im = (float*)alloc(768 * 4);
    float* pow_re = (float*)alloc(768 * 4);
    float* pow_im = (float*)alloc(768 * 4);
    float* coef_re= (float*)alloc(768 * 4);
    float* coef_im= (float*)alloc(768 * 4);
    float* fin    = (float*)alloc((size_t)Bb * 64 * 256 * 4);
    float* carry  = (float*)alloc((size_t)Bb * 64 * 256 * 4);
    f16* WencH = (f16*)alloc((size_t)Hd * INd * 2);
    f16* WencL = (f16*)alloc((size_t)Hd * INd * 2);
    f16* WbuH  = (f16*)alloc((size_t)Kn * 256 * Hd * 2);
    f16* WbuL  = (f16*)alloc((size_t)Kn * 256 * Hd * 2);
    f16* WcH   = (f16*)alloc((size_t)Kn * Hd * 256 * 2);
    f16* WcL   = (f16*)alloc((size_t)Kn * Hd * 256 * 2);
    f16* WgluH = (f16*)alloc((size_t)Kn * Hd * Hd * 2);
    f16* WgluL = (f16*)alloc((size_t)Kn * Hd * Hd * 2);
    f16* WdecH = (f16*)alloc((size_t)OUTd * Hd * 2);
    f16* WdecL = (f16*)alloc((size_t)OUTd * Hd * 2);
    const size_t fixed_bytes = (size_t)(w - (char*)d_ws);

    // per-row activation bytes: h(2048) + uhl(2048) + Bu(1024) + xshl(1024) + xhl(768)
    int G = 1;
    for (; G < 16; G *= 2) {
        size_t Mg = Mrows / G;
        if (fixed_bytes + Mg * 6912ull <= ws_size) break;
    }
    const long Bg = Bb / G;
    const long Mg = Bg * Ll;

    float* h   = (float*)alloc((size_t)Mg * Hd * 4);
    f16*   uh  = (f16*)alloc((size_t)Mg * Hd * 2);   // LN out hi; later g hi; later h hi
    f16*   ul  = (f16*)alloc((size_t)Mg * Hd * 2);
    float* Bu  = (float*)alloc((size_t)Mg * 256 * 4);
    f16*   xsh = (f16*)alloc((size_t)Mg * 256 * 2);
    f16*   xsl = (f16*)alloc((size_t)Mg * 256 * 2);
    f16*   xh  = (f16*)alloc((size_t)Mg * INd * 2);
    f16*   xl  = (f16*)alloc((size_t)Mg * INd * 2);

    // --- prep ---
    prep_lam_k <<<3,    256, 0, stream>>>(Lre, Lim, log_step, lam_re, lam_im,
                                          pow_re, pow_im, coef_re, coef_im);
    prep_bbar_k<<<1536, 256, 0, stream>>>(B_re, B_im, coef_re, coef_im, WbuH, WbuL);
    prep_c_k   <<<1536, 256, 0, stream>>>(C_re, C_im, WcH, WcL);
    split_w_k  <<<6144, 256, 0, stream>>>(W_glu, WgluH, WgluL, (long)Kn * Hd * Hd);
    split_w_k  <<<384,  256, 0, stream>>>(W_enc, WencH, WencL, (long)Hd * INd);
    split_w_k  <<<384,  256, 0, stream>>>(W_dec, WdecH, WdecL, (long)OUTd * Hd);

    const dim3 blk(256);
    const int gy = (int)(Mg / 128);
    for (int g0 = 0; g0 < G; ++g0) {
        const float* xg   = x   + (size_t)g0 * Mg * INd;
        float*       outg = out + (size_t)g0 * Mg * OUTd;

        // split x, then encoder: h = x @ Wenc^T + b_enc
        split_a_k<<<(int)(Mg * INd / 2048), 256, 0, stream>>>(xg, xh, xl, Mg * INd / 8);
        mgemm_k<128, 1><<<dim3(4, gy), blk, 0, stream>>>(
            xh, xl, WencH, WencL, h, 512, INd, b_enc, nullptr, nullptr, nullptr, nullptr);

        for (int k = 0; k < Kn; ++k) {
            ln_k<<<(int)(Mg / 4), 256, 0, stream>>>(h, uh, ul,
                                                    ln_scale + k * 512, ln_bias + k * 512);
            // Bu = u @ Wbu[k]^T (M x 256, K=512)
            mgemm_k<128, 0><<<dim3(2, gy), blk, 0, stream>>>(
                uh, ul, WbuH + (size_t)k * 256 * Hd, WbuL + (size_t)k * 256 * Hd,
                Bu, 256, 512, nullptr, nullptr, nullptr, nullptr, nullptr);
            scan_local_k<<<(int)(Bg * 32), 256, 0, stream>>>(
                Bu, fin, lam_re + k * 128, lam_im + k * 128, (int)Bg);
            scan_carry_k<<<(int)((Bg * 128 + 255) / 256), 256, 0, stream>>>(
                fin, carry, pow_re + k * 128, pow_im + k * 128, (int)Bg);
            scan_final_k<<<(int)(Bg * 32), 256, 0, stream>>>(
                Bu, carry, xsh, xsl, lam_re + k * 128, lam_im + k * 128, (int)Bg);
            // g = gelu(xs @ Wc[k]^T + u*D), written split in place over u
            mgemm_k<128, 2><<<dim3(4, gy), blk, 0, stream>>>(
                xsh, xsl, WcH + (size_t)k * Hd * 256, WcL + (size_t)k * Hd * 256,
                nullptr, 512, 256, Dv + k * 512, uh, ul, uh, ul);
            // h += g * sigmoid(g @ Wglu[k]^T + b_glu)
            mgemm_k<128, 3><<<dim3(4, gy), blk, 0, stream>>>(
                uh, ul, WgluH + (size_t)k * Hd * Hd, WgluL + (size_t)k * Hd * Hd,
                h, 512, 512, b_glu + k * 512, uh, ul, nullptr, nullptr);
        }
        // decoder: split h (reuse uh/ul), out = h @ Wdec^T + b_dec (N=192, BN=64)
        split_a_k<<<(int)(Mg * Hd / 2048), 256, 0, stream>>>(h, uh, ul, Mg * Hd / 8);
        mgemm_k<64, 1><<<dim3(3, gy), blk, 0, stream>>>(
            uh, ul, WdecH, WdecL, outg, 192, 512, b_dec, nullptr, nullptr, nullptr, nullptr);
    }
}